// Round 1
// baseline (3819.198 us; speedup 1.0000x reference)
//
#include <hip/hip_runtime.h>
#include <math.h>

// QRNN3D fused: Conv3d(16->32, 3x3x3, SAME) + tanh/sigmoid + fo-pool over T.
// Shapes: x[4][16][31][128][128], W[32][16][3][3][3], b[32], out[4][16][31][128][128].
// Structure: block = 128 threads = one (b,h,hid) triple, full w-row; thread = one w.
// hid comes from blockIdx.x so weight addresses are wave-uniform -> s_load (scalar
// pipe), leaving VALU for x-loads + FMAs. Recurrence state lives in a register.

namespace {
constexpr int kB = 4, kC = 16, kT = 31, kH = 128, kW = 128, kHid = 16;
constexpr int kHW = kH * kW;     // 16384
constexpr int kTHW = kT * kHW;   // 507904
}

__global__ __launch_bounds__(128) void qrnn_fused(
    const float* __restrict__ x, const float* __restrict__ Wt,
    const float* __restrict__ bias, float* __restrict__ out)
{
    const int w  = threadIdx.x;       // 0..127
    const int o  = blockIdx.x;        // hid channel 0..15
    const int bz = blockIdx.y;        // b*128 + h
    const int b  = bz >> 7;
    const int h  = bz & (kH - 1);

    // w-border: precomputed safe offset + zero mask (no divergent branch, no OOB)
    const int   offL = (w > 0)      ? -1 : 0;
    const int   offR = (w < kW - 1) ?  1 : 0;
    const float mskL = (w > 0)      ? 1.0f : 0.0f;
    const float mskR = (w < kW - 1) ? 1.0f : 0.0f;

    const float* wz = Wt + o * (kC * 27);          // z-gate weights (channel o)
    const float* wf = Wt + (o + kHid) * (kC * 27); // f-gate weights (channel o+16)
    const float zb = bias[o];
    const float fb = bias[o + kHid];

    // h-border: uniform loop-bound clamp
    const int kh0 = (h > 0)      ? 0 : 1;
    const int kh1 = (h < kH - 1) ? 3 : 2;

    const float* xb = x + b * (kC * kTHW);
    float* op = out + (b * kHid + o) * kTHW + h * kW + w;

    float state = 0.0f;
    for (int t = 0; t < kT; ++t) {
        float za = zb, fa = fb;
        // t-border: uniform loop-bound clamp
        const int kd0 = (t > 0)      ? 0 : 1;
        const int kd1 = (t < kT - 1) ? 3 : 2;
        for (int c = 0; c < kC; ++c) {
            const float* xc  = xb + c * kTHW;
            const float* wzc = wz + c * 27;
            const float* wfc = wf + c * 27;
            for (int kd = kd0; kd < kd1; ++kd) {
                const float* xd = xc + (t + kd - 1) * kHW;
                for (int kh = kh0; kh < kh1; ++kh) {
                    const float* row = xd + (h + kh - 1) * kW;
                    const int wi = kd * 9 + kh * 3;
                    const float xm = row[w];
                    const float xl = row[w + offL] * mskL;
                    const float xr = row[w + offR] * mskR;
                    za += xl * wzc[wi] + xm * wzc[wi + 1] + xr * wzc[wi + 2];
                    fa += xl * wfc[wi] + xm * wfc[wi + 1] + xr * wfc[wi + 2];
                }
            }
        }
        const float zt = tanhf(za);
        const float ft = 1.0f / (1.0f + __expf(-fa));
        state = ft * state + (1.0f - ft) * zt;
        op[t * kHW] = state;   // h_t for every t
    }
}

extern "C" void kernel_launch(void* const* d_in, const int* in_sizes, int n_in,
                              void* d_out, int out_size, void* d_ws, size_t ws_size,
                              hipStream_t stream) {
    const float* x    = (const float*)d_in[0];
    const float* Wt   = (const float*)d_in[1];
    const float* bias = (const float*)d_in[2];
    float* out = (float*)d_out;

    dim3 grid(kHid, kB * kH);   // (16, 512) blocks
    dim3 block(kW);             // 128 threads = 2 waves, one w-row
    qrnn_fused<<<grid, block, 0, stream>>>(x, Wt, bias, out);
}

// Round 2
// 1569.051 us; speedup vs baseline: 2.4341x; 2.4341x over previous
//
#include <hip/hip_runtime.h>
#include <math.h>

// QRNN3D fused: Conv3d(16->32, 3x3x3, SAME) + tanh/sigmoid + fo-pool over T.
// R2 restructure: block = (b, h, hid-chunk of 8). Thread = one w column.
// t-chunks of TT=8 give 128 independent accumulator VGPRs (az/af[8][8]) so the
// VALU never stalls on a single dependency chain; each x triple-load feeds 48
// FMAs (was 6). Weights per (c,kh,kd) are 48 wave-uniform floats -> scalar
// loads, amortized over the unrolled tt loop. XCD swizzle keeps h-neighbor
// blocks on one XCD so x re-reads hit that XCD's L2 (working set ~1.6 MB).

namespace {
constexpr int kB = 4, kC = 16, kT = 31, kH = 128, kW = 128, kHid = 16;
constexpr int kHW  = kH * kW;     // 16384
constexpr int kTHW = kT * kHW;    // 507904
constexpr int kGPC = 8;           // hid channels per block (z+f pairs)
}

template <int TT>
__device__ __forceinline__ void do_chunk(
    const float* __restrict__ xb,    // x + b*C*THW
    const float* __restrict__ Wt,    // full weight tensor
    const float* __restrict__ bias,
    int hc0,                          // first hid channel of this block's chunk
    float* __restrict__ op,           // out + (b*HID+hc0)*THW + h*W + w
    int t0, int h, int w,
    int offL, int offR, float mskL, float mskR,
    float state[kGPC])
{
    float az[TT][kGPC], af[TT][kGPC];
#pragma unroll
    for (int tt = 0; tt < TT; ++tt)
#pragma unroll
        for (int o = 0; o < kGPC; ++o) {
            az[tt][o] = bias[hc0 + o];
            af[tt][o] = bias[kHid + hc0 + o];
        }

    for (int c = 0; c < kC; ++c) {
        const float* xc = xb + c * kTHW;
        for (int kh = 0; kh < 3; ++kh) {
            const int hp = h + kh - 1;
            const float hmsk = (hp >= 0 && hp < kH) ? 1.0f : 0.0f;
            const int hcl = min(max(hp, 0), kH - 1);
            const float* xch = xc + hcl * kW + w;   // per-lane row base
            for (int kd = 0; kd < 3; ++kd) {
                // 48 wave-uniform weights for this (c,kh,kd): scalar loads
                float wzv[kGPC][3], wfv[kGPC][3];
#pragma unroll
                for (int o = 0; o < kGPC; ++o)
#pragma unroll
                    for (int j = 0; j < 3; ++j) {
                        const int wi = c * 27 + kd * 9 + kh * 3 + j;
                        wzv[o][j] = Wt[(hc0 + o) * (kC * 27) + wi];
                        wfv[o][j] = Wt[(kHid + hc0 + o) * (kC * 27) + wi];
                    }
#pragma unroll
                for (int tt = 0; tt < TT; ++tt) {
                    const int tp = t0 + tt + kd - 1;
                    const float tmsk = (tp >= 0 && tp < kT) ? hmsk : 0.0f;
                    const int tcl = min(max(tp, 0), kT - 1);
                    const float* row = xch + tcl * kHW;
                    const float xm = row[0]    * tmsk;
                    const float xl = row[offL] * (tmsk * mskL);
                    const float xr = row[offR] * (tmsk * mskR);
#pragma unroll
                    for (int o = 0; o < kGPC; ++o) {
                        az[tt][o] += xl * wzv[o][0] + xm * wzv[o][1] + xr * wzv[o][2];
                        af[tt][o] += xl * wfv[o][0] + xm * wfv[o][1] + xr * wfv[o][2];
                    }
                }
            }
        }
    }

    // epilogue: activations + fo-pool recurrence + store
#pragma unroll
    for (int tt = 0; tt < TT; ++tt) {
#pragma unroll
        for (int o = 0; o < kGPC; ++o) {
            const float z = tanhf(az[tt][o]);
            const float f = 1.0f / (1.0f + __expf(-af[tt][o]));
            state[o] = f * state[o] + (1.0f - f) * z;
            op[o * kTHW + (t0 + tt) * kHW] = state[o];
        }
    }
}

__global__ __launch_bounds__(128, 2) void qrnn_fused(
    const float* __restrict__ x, const float* __restrict__ Wt,
    const float* __restrict__ bias, float* __restrict__ out)
{
    // XCD-aware decode: dispatch round-robins linear block id across 8 XCDs.
    // Give XCD k a contiguous 64-wide bh range so x rows are L2-resident.
    const int id   = blockIdx.x;        // 0..1023
    const int xcd  = id & 7;
    const int j    = id >> 3;           // 0..127
    const int hidc = j & 1;
    const int bh   = xcd * 64 + (j >> 1);   // 0..511
    const int b    = bh >> 7;
    const int h    = bh & (kH - 1);
    const int hc0  = hidc * kGPC;
    const int w    = threadIdx.x;

    const int   offL = (w > 0)      ? -1 : 0;
    const int   offR = (w < kW - 1) ?  1 : 0;
    const float mskL = (w > 0)      ? 1.0f : 0.0f;
    const float mskR = (w < kW - 1) ? 1.0f : 0.0f;

    const float* xb = x + b * (kC * kTHW);
    float* op = out + (b * kHid + hc0) * kTHW + h * kW + w;

    float state[kGPC];
#pragma unroll
    for (int o = 0; o < kGPC; ++o) state[o] = 0.0f;

    // 31 = 8 + 8 + 8 + 7
    do_chunk<8>(xb, Wt, bias, hc0, op,  0, h, w, offL, offR, mskL, mskR, state);
    do_chunk<8>(xb, Wt, bias, hc0, op,  8, h, w, offL, offR, mskL, mskR, state);
    do_chunk<8>(xb, Wt, bias, hc0, op, 16, h, w, offL, offR, mskL, mskR, state);
    do_chunk<7>(xb, Wt, bias, hc0, op, 24, h, w, offL, offR, mskL, mskR, state);
}

extern "C" void kernel_launch(void* const* d_in, const int* in_sizes, int n_in,
                              void* d_out, int out_size, void* d_ws, size_t ws_size,
                              hipStream_t stream) {
    const float* x    = (const float*)d_in[0];
    const float* Wt   = (const float*)d_in[1];
    const float* bias = (const float*)d_in[2];
    float* out = (float*)d_out;

    dim3 grid(2 * kB * kH);   // 1024 blocks: (2 hid-chunks) x (4 b) x (128 h)
    dim3 block(kW);           // 128 threads = one w row
    qrnn_fused<<<grid, block, 0, stream>>>(x, Wt, bias, out);
}

// Round 3
// 287.983 us; speedup vs baseline: 13.2619x; 5.4484x over previous
//
#include <hip/hip_runtime.h>
#include <hip/hip_bf16.h>
#include <math.h>

// QRNN3D fused via bf16 MFMA implicit conv-GEMM + in-register fo-pool.
// GEMM per (b,h,t): D[32 gate-ch][128 pix] = sum over 27 taps of
//   A(tap)[32ch x 16c] * B(tap)[16c x 128pix],  A = weights in VGPRs (t-invariant),
//   B = im2col x-slice in LDS ([wpos][c] c-minor, XOR-swizzled, zero-padded borders).
// C/D layout (32x32x16): col=lane&31=pixel, row=ch=(reg&3)+8*(reg>>2)+4*(lane>>5)
//   => z-gate ch in acc[r], f-gate ch+16 in acc[r+8], same lane: recurrence is
//   per-lane register math; stores coalesced (lane = pixel).
// LDS: 4-slot ring of t-planes (12480 B each, 49920 total) -> 2 blocks/CU.
// One __syncthreads per t: stage(t+2) slot is disjoint from compute(t)'s slots.

namespace {
constexpr int kB = 4, kC = 16, kT = 31, kH = 128, kW = 128, kHid = 16;
constexpr int kHW  = kH * kW;
constexpr int kTHW = kT * kHW;
constexpr int kCS  = 16;            // shorts per wpos (16 c, swizzled, no pad)
constexpr int kRS  = 130 * kCS;     // row stride (shorts) = 2080
constexpr int kPS  = 3 * kRS;       // plane stride (shorts) = 6240 (12480 B)
constexpr int kSlots = 4;
}

typedef __attribute__((ext_vector_type(8)))  short  short8;
typedef __attribute__((ext_vector_type(16))) float  floatx16;

__device__ __forceinline__ unsigned short f2bf(float f) {
    __hip_bfloat16 h = __float2bfloat16(f);   // RTN
    return __builtin_bit_cast(unsigned short, h);
}

// Stage the (t_)-plane of x into LDS slot (t_ & 3): rows h-1..h+1, transposed to
// [wpos][c] with XOR-swizzled c-octets. Out-of-range t_/rows become zeros.
__device__ __forceinline__ void stage_plane(
    unsigned short* __restrict__ lds, const float* __restrict__ xb,
    int t_, int h, int tid)
{
    const int slot = (t_ + 2 * kSlots) & (kSlots - 1);
    unsigned short* pl = lds + slot * kPS;
    const int w  = tid & 127;            // pixel column this thread stages
    const int c0 = (tid >> 7) * 8;       // c-octet 0 or 8
    const int wp = w + 1;                // wpos 1..128 (0 and 129 are halo zeros)
    const int sw = c0 ^ ((wp & 1) * 8);  // bank-conflict XOR swizzle
    const bool tvalid = (t_ >= 0 && t_ < kT);
#pragma unroll
    for (int kh = 0; kh < 3; ++kh) {
        const int hr = h + kh - 1;
        short8 v = {0, 0, 0, 0, 0, 0, 0, 0};
        if (tvalid && hr >= 0 && hr < kH) {     // wave-uniform branch
            const float* src = xb + c0 * kTHW + t_ * kHW + hr * kW + w;
            float f[8];
#pragma unroll
            for (int j = 0; j < 8; ++j) f[j] = src[j * kTHW];
#pragma unroll
            for (int j = 0; j < 8; ++j) v[j] = (short)f2bf(f[j]);
        }
        *(short8*)(pl + kh * kRS + wp * kCS + sw) = v;
    }
}

__global__ __launch_bounds__(256, 2) void qrnn_mfma(
    const float* __restrict__ x, const float* __restrict__ Wt,
    const float* __restrict__ bias, float* __restrict__ out)
{
    __shared__ unsigned short lds[kSlots * kPS];   // 49920 B

    // XCD-aware decode: 64 consecutive h per XCD -> staging rows L2-resident.
    const int id  = blockIdx.x;          // 0..511
    const int bh  = (id & 7) * 64 + (id >> 3);
    const int b   = bh >> 7;
    const int h   = bh & (kH - 1);

    const int tid  = threadIdx.x;
    const int lane = tid & 63;
    const int m    = lane & 31;          // A: gate channel ; B/D: pixel-in-tile
    const int hi   = lane >> 5;
    const int chi  = hi * 8;             // k-octet base (c dimension)
    const int n0   = (tid >> 6) * 32;    // wave's pixel tile base

    const float* xb = x + b * (kC * kTHW);

    // ---- A-operand: all 27 tap fragments of W, bf16, in registers ----
    // A[mch = lane&31][k = chi + j], tap-major matches inner loop order.
    short8 wf[27];
#pragma unroll
    for (int tap = 0; tap < 27; ++tap) {
        short8 v;
#pragma unroll
        for (int j = 0; j < 8; ++j)
            v[j] = (short)f2bf(Wt[m * (kC * 27) + (chi + j) * 27 + tap]);
        wf[tap] = v;
    }

    // ---- per-lane recurrence state, biases, output offsets ----
    float st[8], zb[8], fbv[8];
    int ooff[8];
    const int P = n0 + m;                // this lane's pixel (w coordinate)
#pragma unroll
    for (int r = 0; r < 8; ++r) {
        const int hid = (r & 3) + 8 * (r >> 2) + 4 * hi;   // D-row for reg r
        zb[r]  = bias[hid];
        fbv[r] = bias[kHid + hid];
        st[r]  = 0.0f;
        ooff[r] = ((b * kHid + hid) * kT) * kHW + h * kW + P;
    }

    // ---- B-operand lane base addresses (XOR swizzle splits kw parity) ----
    unsigned short* bA = lds + P * kCS       + (chi ^ ((P & 1) * 8));       // kw=0 (+64B: kw=2)
    unsigned short* bB = lds + (P + 1) * kCS + (chi ^ (((P + 1) & 1) * 8)); // kw=1

    // ---- prologue: planes t=-1 (zeros), t=0; halo columns of all slots ----
    stage_plane(lds, xb, -1, h, tid);
    stage_plane(lds, xb,  0, h, tid);
    if (tid < 48) {   // zero wpos 0 and 129, all slots/rows/octets
        const int s = tid / 12, rem = tid % 12;
        const int row = rem >> 2, q = rem & 3;
        const int wp = (q & 1) * 129;
        const int c0 = (q >> 1) * 8;
        const short8 z = {0, 0, 0, 0, 0, 0, 0, 0};
        *(short8*)(lds + s * kPS + row * kRS + wp * kCS + (c0 ^ ((wp & 1) * 8))) = z;
    }

    for (int t = 0; t < kT; ++t) {
        stage_plane(lds, xb, t + 1, h, tid);   // slot (t+1)&3, disjoint from t-1..t+1? (t+1 IS computed-from; barrier below orders it)
        __syncthreads();

        floatx16 acc = {0,0,0,0,0,0,0,0,0,0,0,0,0,0,0,0};
#pragma unroll
        for (int kd = 0; kd < 3; ++kd) {
            const int soff = ((t + kd + 2 * kSlots - 1) & (kSlots - 1)) * kPS;
#pragma unroll
            for (int kh = 0; kh < 3; ++kh) {
                const int o = soff + kh * kRS;
                const short8 b0 = *(const short8*)(bA + o);        // kw=0 -> x[P-1]
                const short8 b1 = *(const short8*)(bB + o);        // kw=1 -> x[P]
                const short8 b2 = *(const short8*)(bA + o + 2 * kCS); // kw=2 -> x[P+1]
                acc = __builtin_amdgcn_mfma_f32_32x32x16_bf16(wf[kd*9 + kh*3 + 0], b0, acc, 0, 0, 0);
                acc = __builtin_amdgcn_mfma_f32_32x32x16_bf16(wf[kd*9 + kh*3 + 1], b1, acc, 0, 0, 0);
                acc = __builtin_amdgcn_mfma_f32_32x32x16_bf16(wf[kd*9 + kh*3 + 2], b2, acc, 0, 0, 0);
            }
        }

        // epilogue: gates -> activations -> fo-pool -> coalesced store
#pragma unroll
        for (int r = 0; r < 8; ++r) {
            const float zp = acc[r]     + zb[r];
            const float fp = acc[r + 8] + fbv[r];
            const float e2 = __expf(2.0f * zp);
            const float z  = 1.0f - 2.0f * __builtin_amdgcn_rcpf(e2 + 1.0f);  // tanh(zp)
            const float f  = __builtin_amdgcn_rcpf(1.0f + __expf(-fp));       // sigmoid(fp)
            st[r] = z + f * (st[r] - z);
            out[ooff[r] + t * kHW] = st[r];
        }
    }
}

extern "C" void kernel_launch(void* const* d_in, const int* in_sizes, int n_in,
                              void* d_out, int out_size, void* d_ws, size_t ws_size,
                              hipStream_t stream) {
    const float* x    = (const float*)d_in[0];
    const float* Wt   = (const float*)d_in[1];
    const float* bias = (const float*)d_in[2];
    float* out = (float*)d_out;

    qrnn_mfma<<<dim3(kB * kH), dim3(256), 0, stream>>>(x, Wt, bias, out);
}